// Round 8
// baseline (220.472 us; speedup 1.0000x reference)
//
#include <hip/hip_runtime.h>
#include <hip/hip_bf16.h>
#include <math.h>

#define BATCH 8
#define CI    256
#define HWSZ  1600
#define DDIM  128
#define NHEAD 8
#define DH    16
#define NPTS  32768
#define KCSP  5            // attention key-split
#define NKEY  320          // keys per attention block (1600/5)
#define XK_STR 24          // LDS key-row stride in shorts

typedef __attribute__((ext_vector_type(4))) short s16x4;
typedef __attribute__((ext_vector_type(4))) float f32x4;

#if defined(__HIP_DEVICE_COMPILE__)
  #if __has_builtin(__builtin_amdgcn_mfma_f32_16x16x16bf16_1k)
    #define MFMA16(a, b, c) __builtin_amdgcn_mfma_f32_16x16x16bf16_1k(a, b, c, 0, 0, 0)
  #elif __has_builtin(__builtin_amdgcn_mfma_f32_16x16x16_bf16)
    #define MFMA16(a, b, c) __builtin_amdgcn_mfma_f32_16x16x16_bf16(a, b, c, 0, 0, 0)
  #else
    #error "no 16x16x16 bf16 mfma builtin on this device target"
  #endif
#else
  #define MFMA16(a, b, c) (c)
#endif

union fragu {
  s16x4 s;
  unsigned int u[2];
  uint2 u2;
};

// R4/R5/R7-proven RNE packed f32->bf16x2 (R6's inline-asm variant NaN'd).
__device__ __forceinline__ unsigned int pk_bf2(float a, float b) {
  __hip_bfloat162 h = __float22bfloat162_rn(make_float2(a, b));
  return *(unsigned int*)&h;
}

__device__ __forceinline__ float exp2a(float x) {
#if defined(__HIP_DEVICE_COMPILE__)
  #if __has_builtin(__builtin_amdgcn_exp2f)
  return __builtin_amdgcn_exp2f(x);
  #else
  return exp2f(x);
  #endif
#else
  return x;
#endif
}

__device__ __forceinline__ float bf2f(unsigned short u) {
  return __uint_as_float(((unsigned int)u) << 16);
}
__device__ __forceinline__ float bflo(unsigned int u) {
  return __uint_as_float(u << 16);
}
__device__ __forceinline__ float bfhi(unsigned int u) {
  return __uint_as_float(u & 0xFFFF0000u);
}

// ---------------- KA: blocks 0..199 linear1+l2norm; 200..711 cloud -------
// img path: W1 A-frags self-staged into LDS (L2-hot, ~500 cyc/wave), then
// MFMA with direct-global B-frags, l2norm epilogue -> tokh bf16.
// cloud path: one row per wave (bid wave-uniform -> register bins), 16
// rows/wave x 512 blocks; per-block GeM partials (write-once).
__global__ __launch_bounds__(256) void kA(
    const float* __restrict__ img, const float* __restrict__ W1,
    const float* __restrict__ b1, const float* __restrict__ cf,
    const int* __restrict__ bids, unsigned short* __restrict__ tokh,
    float* __restrict__ cloud_out, float* __restrict__ gaw,
    float* __restrict__ cntw) {
  __shared__ union {
    unsigned short w1f[32768];                         // 64 KB frag layout
    struct { float ga[4][BATCH * DDIM]; int gcnt[4][BATCH]; } c;
  } u;
  int t = threadIdx.x, lane = t & 63, w = t >> 6;
  int lm = lane & 15, qd = lane >> 4;
  int blk = blockIdx.x;

  if (blk < 200) {
    // stage W1 frags: entry e -> A[m=dt*16+elm][k quad eqd] (R5-proven map)
#pragma unroll 4
    for (int i = 0; i < 32; i++) {
      int e = i * 256 + t;
      int el = e & 63, elm = el & 15, eqd = el >> 4;
      int ks = (e >> 6) & 15, dt = e >> 10;
      const float* p = W1 + (size_t)(ks * 16 + 4 * eqd) * DDIM + dt * 16 + elm;
      float f0 = p[0], f1 = p[DDIM], f2 = p[2 * DDIM], f3 = p[3 * DDIM];
      *(uint2*)&u.w1f[(size_t)e * 4] = make_uint2(pk_bf2(f0, f1), pk_bf2(f2, f3));
    }
    int b = blk / 25, n0 = (blk % 25) * 64;
    int tok = n0 + w * 16 + lm;
    const float* imgb = img + (size_t)b * CI * HWSZ;
    float fv[16][4];
#pragma unroll
    for (int ks = 0; ks < 16; ks++) {
      const float* p = imgb + (size_t)(ks * 16 + 4 * qd) * HWSZ + tok;
      fv[ks][0] = p[0];        fv[ks][1] = p[HWSZ];
      fv[ks][2] = p[2 * HWSZ]; fv[ks][3] = p[3 * HWSZ];
    }
    __syncthreads();
    f32x4 acc[8];
#pragma unroll
    for (int dt = 0; dt < 8; dt++) acc[dt] = (f32x4){0.f, 0.f, 0.f, 0.f};
#pragma unroll
    for (int ks = 0; ks < 16; ks++) {
      fragu bf_;
      bf_.u[0] = pk_bf2(fv[ks][0], fv[ks][1]);
      bf_.u[1] = pk_bf2(fv[ks][2], fv[ks][3]);
#pragma unroll
      for (int dt = 0; dt < 8; dt++) {
        s16x4 af = *(const s16x4*)&u.w1f[((dt * 16 + ks) * 64 + lane) * 4];
        acc[dt] = MFMA16(af, bf_.s, acc[dt]);
      }
    }
    float vals[8][4];
    float ss = 0.f;
#pragma unroll
    for (int dt = 0; dt < 8; dt++)
#pragma unroll
      for (int r = 0; r < 4; r++) {
        float v = acc[dt][r] + b1[dt * 16 + 4 * qd + r];
        vals[dt][r] = v;
        ss += v * v;
      }
    ss += __shfl_xor(ss, 16);
    ss += __shfl_xor(ss, 32);
    float inv = 1.f / fmaxf(sqrtf(ss), 1e-12f);
#pragma unroll
    for (int dt = 0; dt < 8; dt++) {
      uint2 pk = make_uint2(pk_bf2(vals[dt][0] * inv, vals[dt][1] * inv),
                            pk_bf2(vals[dt][2] * inv, vals[dt][3] * inv));
      *(uint2*)&tokh[(((size_t)b * NHEAD + dt) * HWSZ + tok) * DH + 4 * qd] = pk;
    }
    return;
  }

  // ---- cloud ----
  int bk = blk - 200;                         // 0..511
  int r0 = (bk * 4 + w) * 16;
  float a0x = 0.f, a0y = 0.f, a1x = 0.f, a1y = 0.f;
  float a2x = 0.f, a2y = 0.f, a3x = 0.f, a3y = 0.f;
  float a4x = 0.f, a4y = 0.f, a5x = 0.f, a5y = 0.f;
  float a6x = 0.f, a6y = 0.f, a7x = 0.f, a7y = 0.f;
  int c0 = 0, c1 = 0, c2 = 0, c3 = 0, c4 = 0, c5 = 0, c6 = 0, c7 = 0;
  for (int i = 0; i < 16; i++) {
    int r = r0 + i;
    float2 v = *(const float2*)(cf + (size_t)r * DDIM + lane * 2);
    float ss = v.x * v.x + v.y * v.y;
    ss += __shfl_xor(ss, 1);  ss += __shfl_xor(ss, 2);  ss += __shfl_xor(ss, 4);
    ss += __shfl_xor(ss, 8);  ss += __shfl_xor(ss, 16); ss += __shfl_xor(ss, 32);
    float sc = 1.f / fmaxf(sqrtf(ss), 1e-12f);
    float y0 = v.x * sc, y1 = v.y * sc;
    *(float2*)(cloud_out + (size_t)r * DDIM + lane * 2) = make_float2(y0, y1);
    float p0 = fmaxf(y0, 1e-6f), p1 = fmaxf(y1, 1e-6f);
    p0 = p0 * p0 * p0;
    p1 = p1 * p1 * p1;
    switch (bids[r]) {
      case 0: a0x += p0; a0y += p1; c0++; break;
      case 1: a1x += p0; a1y += p1; c1++; break;
      case 2: a2x += p0; a2y += p1; c2++; break;
      case 3: a3x += p0; a3y += p1; c3++; break;
      case 4: a4x += p0; a4y += p1; c4++; break;
      case 5: a5x += p0; a5y += p1; c5++; break;
      case 6: a6x += p0; a6y += p1; c6++; break;
      default: a7x += p0; a7y += p1; c7++; break;
    }
  }
  float* gw = &u.c.ga[w][0];
  *(float2*)&gw[0 * DDIM + 2 * lane] = make_float2(a0x, a0y);
  *(float2*)&gw[1 * DDIM + 2 * lane] = make_float2(a1x, a1y);
  *(float2*)&gw[2 * DDIM + 2 * lane] = make_float2(a2x, a2y);
  *(float2*)&gw[3 * DDIM + 2 * lane] = make_float2(a3x, a3y);
  *(float2*)&gw[4 * DDIM + 2 * lane] = make_float2(a4x, a4y);
  *(float2*)&gw[5 * DDIM + 2 * lane] = make_float2(a5x, a5y);
  *(float2*)&gw[6 * DDIM + 2 * lane] = make_float2(a6x, a6y);
  *(float2*)&gw[7 * DDIM + 2 * lane] = make_float2(a7x, a7y);
  if (lane == 0) {
    u.c.gcnt[w][0] = c0; u.c.gcnt[w][1] = c1; u.c.gcnt[w][2] = c2;
    u.c.gcnt[w][3] = c3; u.c.gcnt[w][4] = c4; u.c.gcnt[w][5] = c5;
    u.c.gcnt[w][6] = c6; u.c.gcnt[w][7] = c7;
  }
  __syncthreads();
  for (int j = t; j < BATCH * DDIM; j += 256)
    gaw[(size_t)bk * 1024 + j] =
        u.c.ga[0][j] + u.c.ga[1][j] + u.c.ga[2][j] + u.c.ga[3][j];
  if (t < BATCH)
    cntw[bk * 8 + t] = (float)(u.c.gcnt[0][t] + u.c.gcnt[1][t] +
                               u.c.gcnt[2][t] + u.c.gcnt[3][t]);
}

// ---------------- KB: MFMA flash attention, key-split 5x -----------------
// grid (320,13) x 128 thr: x = bh*5 + kc (320 keys each), y = 128-q strip.
// LDS 15.36 KB -> 10 blocks/CU resident (vs 22% occupancy at R7's 19.2 KB
// / 6.5 blocks). Writes UNNORMALIZED bf16 num + f32 den partials.
__global__ __launch_bounds__(128) void kB(
    const unsigned short* __restrict__ tokh, unsigned short* __restrict__ numh,
    float* __restrict__ denw) {
  __shared__ unsigned short sXk[NKEY * XK_STR];   // 15360 B
  const int gx = blockIdx.x;
  const int bh = gx / KCSP, kc = gx - bh * KCSP;
  const int t = threadIdx.x;
  const int lane = t & 63;
  const int w = t >> 6;
  const int lm = lane & 15;
  const int qd = lane >> 4;
  const unsigned short* tok = tokh + (size_t)bh * (HWSZ * DH);
  const int qw = blockIdx.y * 128 + w * 64;
  const bool active = qw < HWSZ;

  const float SCL = 0.25f * 1.44269504088896f;
  s16x4 qf[4];
  f32x4 oacc[4];
  float den[4];
  if (active) {
#pragma unroll
    for (int s = 0; s < 4; s++) {
      const unsigned short* qs = tok + (size_t)(qw + s * 16 + lm) * DH + 4 * qd;
      s16x4 raw = *(const s16x4*)qs;
      fragu q;
      q.u[0] = pk_bf2(bf2f((unsigned short)raw[0]) * SCL,
                      bf2f((unsigned short)raw[1]) * SCL);
      q.u[1] = pk_bf2(bf2f((unsigned short)raw[2]) * SCL,
                      bf2f((unsigned short)raw[3]) * SCL);
      qf[s] = q.s;
      oacc[s] = (f32x4){0.f, 0.f, 0.f, 0.f};
      den[s] = 0.f;
    }
  }

  for (int i = t; i < 2 * NKEY; i += 128) {
    int r = i >> 1, hf = i & 1;
    *(uint4*)&sXk[r * XK_STR + hf * 8] =
        *(const uint4*)(tok + (size_t)(kc * NKEY + r) * DH + hf * 8);
  }
  __syncthreads();
  if (active) {
#pragma unroll 1
    for (int st = 0; st < NKEY / 16; st++) {
      int n0 = st * 16;
      s16x4 kf = *(const s16x4*)&sXk[(n0 + lm) * XK_STR + 4 * qd];
      const unsigned short* vb = &sXk[(n0 + 4 * qd) * XK_STR + lm];
      fragu vv;
      vv.u[0] = (unsigned int)vb[0] | ((unsigned int)vb[XK_STR] << 16);
      vv.u[1] = (unsigned int)vb[2 * XK_STR] | ((unsigned int)vb[3 * XK_STR] << 16);
      f32x4 sc[4];
#pragma unroll
      for (int s = 0; s < 4; s++)
        sc[s] = MFMA16(kf, qf[s], ((f32x4){0.f, 0.f, 0.f, 0.f}));
      fragu pf[4];
#pragma unroll
      for (int s = 0; s < 4; s++) {
        float e0 = exp2a(sc[s].x), e1 = exp2a(sc[s].y);
        float e2 = exp2a(sc[s].z), e3 = exp2a(sc[s].w);
        den[s] += (e0 + e1) + (e2 + e3);
        pf[s].u[0] = pk_bf2(e0, e1);
        pf[s].u[1] = pk_bf2(e2, e3);
      }
#pragma unroll
      for (int s = 0; s < 4; s++)
        oacc[s] = MFMA16(vv.s, pf[s].s, oacc[s]);
    }
  }

  if (active) {
#pragma unroll
    for (int s = 0; s < 4; s++) {
      float d = den[s];
      d += __shfl_xor(d, 16);
      d += __shfl_xor(d, 32);
      size_t q = (size_t)qw + s * 16 + lm;
      unsigned short* np =
          numh + ((size_t)(bh * KCSP + kc) * HWSZ + q) * 16 + 4 * qd;
      *(uint2*)np = make_uint2(pk_bf2(oacc[s].x, oacc[s].y),
                               pk_bf2(oacc[s].z, oacc[s].w));
      if (qd == 0) denw[(size_t)(bh * KCSP + kc) * HWSZ + q] = d;
    }
  }
}

// ---------------- KC: combine partials + MFMA linear2 + img GeM partial --
__global__ __launch_bounds__(256) void kC(
    const unsigned short* __restrict__ numh, const float* __restrict__ denw,
    const float* __restrict__ W2, const float* __restrict__ b2,
    float* __restrict__ img_out, float* __restrict__ gawi) {
  __shared__ union { unsigned short w2f[32768]; float red[4][256]; } u;
  int t = threadIdx.x, lane = t & 63, w = t >> 6;
  int lm = lane & 15, qd = lane >> 4;
  // stage W2 frags (R5-proven map)
#pragma unroll 4
  for (int i = 0; i < 32; i++) {
    int e = i * 256 + t;
    int el = e & 63, elm = el & 15, eqd = el >> 4;
    int ks = (e >> 6) & 7, ct = e >> 9;
    const float* p = W2 + (size_t)(ks * 16 + 4 * eqd) * CI + ct * 16 + elm;
    float f0 = p[0], f1 = p[CI], f2 = p[2 * CI], f3 = p[3 * CI];
    *(uint2*)&u.w2f[(size_t)e * 4] = make_uint2(pk_bf2(f0, f1), pk_bf2(f2, f3));
  }
  int blk = blockIdx.x;                      // 200 = 8b x 25 strips of 64
  int b = blk / 25, n0 = (blk % 25) * 64;
  int tok = n0 + w * 16 + lm;
  __syncthreads();
  f32x4 acc[16];
#pragma unroll
  for (int ct = 0; ct < 16; ct++) acc[ct] = (f32x4){0.f, 0.f, 0.f, 0.f};
#pragma unroll 2
  for (int ks = 0; ks < 8; ks++) {
    size_t base5 = (size_t)(b * 8 + ks) * KCSP;
    float s0 = 0.f, s1 = 0.f, s2 = 0.f, s3 = 0.f, dsum = 0.f;
#pragma unroll
    for (int kc = 0; kc < KCSP; kc++) {
      uint2 nv = *(const uint2*)&numh[((base5 + kc) * HWSZ + tok) * 16 + 4 * qd];
      s0 += bflo(nv.x); s1 += bfhi(nv.x);
      s2 += bflo(nv.y); s3 += bfhi(nv.y);
      dsum += denw[(base5 + kc) * HWSZ + tok];
    }
    float inv = 1.f / dsum;
    fragu bf_;
    bf_.u[0] = pk_bf2(s0 * inv, s1 * inv);
    bf_.u[1] = pk_bf2(s2 * inv, s3 * inv);
#pragma unroll
    for (int ct = 0; ct < 16; ct++) {
      s16x4 af = *(const s16x4*)&u.w2f[((ct * 8 + ks) * 64 + lane) * 4];
      acc[ct] = MFMA16(af, bf_.s, acc[ct]);
    }
  }
  __syncthreads();   // all w2f reads done before red overwrite
  float* ob = img_out + (size_t)b * CI * HWSZ;
#pragma unroll
  for (int ct = 0; ct < 16; ct++) {
#pragma unroll
    for (int r = 0; r < 4; r++) {
      int ci = ct * 16 + 4 * qd + r;
      float v = acc[ct][r] + b2[ci];
      ob[(size_t)ci * HWSZ + tok] = v;
      float c = fmaxf(v, 1e-6f);
      float p = c * c * c;
      p += __shfl_xor(p, 1); p += __shfl_xor(p, 2);
      p += __shfl_xor(p, 4); p += __shfl_xor(p, 8);
      if (lm == 0) u.red[w][ci] = p;
    }
  }
  __syncthreads();
  gawi[(size_t)blk * 256 + t] =
      u.red[0][t] + u.red[1][t] + u.red[2][t] + u.red[3][t];
}

// ---------------- KD: finalize both GeMs ---------------------------------
__global__ __launch_bounds__(256) void kD(
    const float* __restrict__ gawi, const float* __restrict__ gaw,
    const float* __restrict__ cntw, float* __restrict__ image_gem,
    float* __restrict__ cloud_gem) {
  __shared__ float cw[8][8];
  int t = threadIdx.x;
  int blk = blockIdx.x;
  if (blk < 8) {
    int row = blk * 256 + t;                 // b*256 + ci
    int b = row >> 8, ci = row & 255;
    float s = 0.f;
#pragma unroll 5
    for (int k = 0; k < 25; k++) s += gawi[(size_t)(b * 25 + k) * 256 + ci];
    image_gem[row] = powf(s * (1.f / (float)HWSZ), 1.f / 3.f);
  } else {
    if (t < 64) {
      int bb = t & 7, ch = t >> 3;
      float s = 0.f;
      for (int i = 0; i < 64; i++) s += cntw[(ch * 64 + i) * 8 + bb];
      cw[ch][bb] = s;
    }
    __syncthreads();
    int j = (blk - 8) * 256 + t;             // 0..1023
    float s = 0.f;
#pragma unroll 4
    for (int k = 0; k < 512; k++) s += gaw[(size_t)k * 1024 + j];
    int b = j >> 7;
    float cb = cw[0][b] + cw[1][b] + cw[2][b] + cw[3][b] +
               cw[4][b] + cw[5][b] + cw[6][b] + cw[7][b];
    cloud_gem[j] = powf(s / fmaxf(cb, 1.f), 1.f / 3.f);
  }
}

extern "C" void kernel_launch(void* const* d_in, const int* in_sizes, int n_in,
                              void* d_out, int out_size, void* d_ws, size_t ws_size,
                              hipStream_t stream) {
  const float* image_feat = (const float*)d_in[0];
  const float* cloud_feat = (const float*)d_in[1];
  const int*   cloud_bids = (const int*)d_in[2];
  const float* W1 = (const float*)d_in[3];
  const float* b1 = (const float*)d_in[4];
  const float* W2 = (const float*)d_in[5];
  const float* b2 = (const float*)d_in[6];

  float* out = (float*)d_out;
  float* img_out   = out;                                  // [8,256,40,40]
  float* cloud_out = out + 3276800;                        // [32768,128]
  float* image_gem = out + 3276800 + 4194304;              // [8,256]
  float* cloud_gem = image_gem + 2048;                     // [8,128]

  char* ws = (char*)d_ws;
  unsigned short* tokh = (unsigned short*)ws;              // bf16 [64][1600][16]   3,276,800 B
  unsigned short* numh = (unsigned short*)(ws + 3276800);  // bf16 [320][1600][16] 16,384,000 B
  float* denw = (float*)(ws + 19660800);                   // f32  [320][1600]      2,048,000 B
  float* gaw  = (float*)(ws + 21708800);                   // f32  [512][1024]      2,097,152 B
  float* cntw = (float*)(ws + 23805952);                   // f32  [512][8]            16,384 B
  float* gawi = (float*)(ws + 23822336);                   // f32  [200][256]         204,800 B

  kA<<<dim3(712), dim3(256), 0, stream>>>(image_feat, W1, b1, cloud_feat,
                                          cloud_bids, tokh, cloud_out, gaw, cntw);
  kB<<<dim3(320, 13), dim3(128), 0, stream>>>(tokh, numh, denw);
  kC<<<dim3(200), dim3(256), 0, stream>>>(numh, denw, W2, b2, img_out, gawi);
  kD<<<dim3(12), dim3(256), 0, stream>>>(gawi, gaw, cntw, image_gem, cloud_gem);
}